// Round 4
// baseline (816.416 us; speedup 1.0000x reference)
//
#include <hip/hip_runtime.h>
#include <math.h>

#define N_E 2048
#define N_U 4096
#define N_SVC 1024
#define KT 16
#define STRX (KT*N_E*32)   // per-stream x/y buffer stride (floats)

typedef __attribute__((ext_vector_type(8))) short short8;   // 8 bf16 (4 VGPRs)
typedef __attribute__((ext_vector_type(4))) float f32x4;

__device__ __forceinline__ float sigf(float x){ return 1.0f/(1.0f+__expf(-x)); }
__device__ __forceinline__ float tanhfast(float x){ return 1.0f - 2.0f/(__expf(2.0f*x)+1.0f); }
__device__ __forceinline__ short f2bf(float f){
  union { float f; unsigned u; } x; x.f = f;
  unsigned r = x.u + 0x7FFFu + ((x.u >> 16) & 1u);
  return (short)(r >> 16);
}
// expm1 via 4-term Taylor: valid (rel err <1e-5) for d in [0, 0.5]; d here is ~<0.05
__device__ __forceinline__ float expm1t(float d){
  float t = fmaf(d, 1.f/24.f, 1.f/6.f);
  t = fmaf(d, t, 0.5f);
  t = fmaf(d, t, 1.f);
  return d*t;
}

// ---------------- embeddings: srv_emb (2048x32), svc_emb (1024x32) ----------------
__global__ void k_embed(const int* __restrict__ srv_attr, const int* __restrict__ svc_attr,
                        const float* __restrict__ srv_tab0, const float* __restrict__ srv_lvl,
                        const float* __restrict__ svc_tab0, const float* __restrict__ svc_lvl,
                        float* __restrict__ srv_emb, float* __restrict__ svc_emb) {
  int idx = blockIdx.x*256 + threadIdx.x;       // (2048+1024) rows * 32 cols
  int r = idx >> 5, c = idx & 31;
  int seg = c >> 3, cc = c & 7;
  if (r < N_E) {
    int a = srv_attr[r*4 + seg];
    srv_emb[r*32 + c] = (seg==0) ? srv_tab0[a*8+cc] : srv_lvl[((seg-1)*10 + a)*8 + cc];
  } else {
    int r2 = r - N_E;
    if (r2 < N_SVC) {
      int a = svc_attr[r2*4 + seg];
      svc_emb[r2*32 + c] = (seg==0) ? svc_tab0[a*8+cc] : svc_lvl[((seg-1)*10 + a)*8 + cc];
    }
  }
}

// ---------------- LSTM: 16 lanes per user, lane j owns hidden unit j ----------------
__global__ __launch_bounds__(256) void k_lstm(const float* __restrict__ usr_tab, const float* __restrict__ tra,
                       const float* __restrict__ Wih, const float* __restrict__ Whh,
                       const float* __restrict__ bih, const float* __restrict__ bhh,
                       float* __restrict__ tra_feat) {
  __shared__ float sWih[64*12];
  __shared__ float sWhh[64*16];
  __shared__ float sB[64];
  int tid = threadIdx.x;
  for (int i = tid; i < 64*12; i += 256) sWih[i] = Wih[i];
  for (int i = tid; i < 64*16; i += 256) sWhh[i] = Whh[i];
  if (tid < 64) sB[tid] = bih[tid] + bhh[tid];
  __syncthreads();
  int j  = tid & 15;
  int u  = blockIdx.x*16 + (tid >> 4);
  float xe[8];
  #pragma unroll
  for (int k=0;k<8;k++) xe[k] = usr_tab[u*8+k];
  float h = 0.f, c = 0.f;
  for (int t=0;t<KT;t++) {
    float gi = sB[j], gf = sB[16+j], gg = sB[32+j], go = sB[48+j];
    #pragma unroll
    for (int k=0;k<8;k++) {
      float v = xe[k];
      gi += sWih[j*12+k]*v;      gf += sWih[(16+j)*12+k]*v;
      gg += sWih[(32+j)*12+k]*v; go += sWih[(48+j)*12+k]*v;
    }
    #pragma unroll
    for (int k=0;k<4;k++) {
      float v = tra[((size_t)t*N_U + u)*4 + k];
      gi += sWih[j*12+8+k]*v;      gf += sWih[(16+j)*12+8+k]*v;
      gg += sWih[(32+j)*12+8+k]*v; go += sWih[(48+j)*12+8+k]*v;
    }
    #pragma unroll
    for (int jj=0;jj<16;jj++) {
      float hv = __shfl(h, jj, 16);
      gi += sWhh[j*16+jj]*hv;      gf += sWhh[(16+j)*16+jj]*hv;
      gg += sWhh[(32+j)*16+jj]*hv; go += sWhh[(48+j)*16+jj]*hv;
    }
    c = sigf(gf)*c + sigf(gi)*tanhfast(gg);
    h = sigf(go)*tanhfast(c);
  }
  tra_feat[u*16 + j] = h;
}

// ---------------- ep/ea = edge @ peW^T + b : (16,2048,8) x2 ----------------
__global__ void k_pe(const float* __restrict__ edge,
                     const float* __restrict__ Wp, const float* __restrict__ bp,
                     const float* __restrict__ Wa, const float* __restrict__ ba,
                     float* __restrict__ ep, float* __restrict__ ea) {
  int idx = blockIdx.x*256 + threadIdx.x;        // s(1) t(4) n(11) c(3) = 19 bits
  int c = idx & 7; int rest = idx >> 3;
  int n = rest & 2047; rest >>= 11; int t = rest & 15; int s = rest >> 4;
  const float* W = s ? Wa : Wp; const float* b = s ? ba : bp;
  const float* e = edge + ((size_t)t*N_E + n)*11;
  float acc = b[c];
  #pragma unroll
  for (int k=0;k<11;k++) acc += e[k]*W[c*11+k];
  (s ? ea : ep)[((size_t)t*N_E + n)*8 + c] = acc;
}

// ---------------- T[t] = ep[t] @ (E2[t] . E1) : (16,2048,8) x2 ----------------
__global__ void k_T(const float* __restrict__ epp, const float* __restrict__ epa,
                    const float* __restrict__ E1p, const float* __restrict__ E2p,
                    const float* __restrict__ E1a, const float* __restrict__ E2a,
                    float* __restrict__ Tp, float* __restrict__ Ta) {
  __shared__ float sM[64];
  int s = blockIdx.x >> 4, t = blockIdx.x & 15;
  const float* E1 = s ? E1a : E1p;
  const float* E2 = s ? E2a : E2p;
  const float* ep = (s ? epa : epp) + (size_t)t*N_E*8;
  float* T = (s ? Ta : Tp) + (size_t)t*N_E*8;
  int tid = threadIdx.x;
  if (tid < 64) {
    int u = tid >> 3, v = tid & 7;
    float m = 0.f;
    #pragma unroll
    for (int o=0;o<8;o++) m += E2[t*8+o]*E1[(o*8+u)*8+v];
    sM[u*8+v] = m;
  }
  __syncthreads();
  for (int e2 = tid; e2 < N_E*8; e2 += 256) {
    int i = e2 >> 3, v = e2 & 7;
    float acc = 0.f;
    #pragma unroll
    for (int u=0;u<8;u++) acc += ep[i*8+u]*sM[u*8+v];
    T[e2] = acc;
  }
}

// --------- softmax row partials: partC[s,t,sp,n] = sum_{m in split sp} exp(relu(T[n].ep[m])) ---------
__global__ __launch_bounds__(256) void k_stats(const float* __restrict__ Tp, const float* __restrict__ Ta,
                        const float* __restrict__ epp, const float* __restrict__ epa,
                        float* __restrict__ partC) {
  __shared__ float sE[256*8];   // 8 KiB
  int s = blockIdx.z, t = blockIdx.y;
  int ntile = blockIdx.x & 7, sp = blockIdx.x >> 3;
  int n = ntile*256 + threadIdx.x;
  const float* T = (s ? Ta : Tp) + ((size_t)t*N_E + n)*8;
  const float* E = (s ? epa : epp) + (size_t)t*N_E*8;
  int tid = threadIdx.x;
  float tr[8];
  {
    const float4* gt = (const float4*)T;
    float4 a = gt[0], b = gt[1];
    tr[0]=a.x; tr[1]=a.y; tr[2]=a.z; tr[3]=a.w;
    tr[4]=b.x; tr[5]=b.y; tr[6]=b.z; tr[7]=b.w;
  }
  int m0 = sp*256;
  {
    const float4* ge = (const float4*)(E + (size_t)m0*8);
    float4* se = (float4*)sE;
    for (int i = tid; i < 512; i += 256) se[i] = ge[i];
  }
  __syncthreads();
  float psum = 0.f;
  #pragma unroll 4
  for (int m = 0; m < 256; m++) {
    float d = 0.f;
    #pragma unroll
    for (int v=0;v<8;v++) d = fmaf(sE[m*8+v], tr[v], d);
    psum += __expf(fmaxf(d, 0.f));
  }
  partC[(((size_t)s*KT + t)*8 + sp)*N_E + n] = psum;
}

// ---------------- Zinv = 1 / (sum of 8 partials) ----------------
__global__ void k_zinv(const float* __restrict__ partC, float* __restrict__ Z) {
  int i = blockIdx.x*256 + threadIdx.x;   // 2*16*2048 = 65536
  int n = i & 2047; int st = i >> 11;
  float a = 0.f;
  #pragma unroll
  for (int sp=0;sp<8;sp++) a += partC[((size_t)st*8 + sp)*N_E + n];
  Z[(size_t)st*N_E + n] = 1.0f/a;
}

// ---------------- x0 = proj(load / svc_tot) : (16,2048,32) x2 ----------------
__global__ void k_proj(const float* __restrict__ loadx, const float* __restrict__ svcx,
                       const float* __restrict__ Wp, const float* __restrict__ bp,
                       const float* __restrict__ Wa, const float* __restrict__ ba,
                       float* __restrict__ x0p, float* __restrict__ x0a) {
  int idx = blockIdx.x*256 + threadIdx.x;        // s t n g : 21 bits
  int g = idx & 31; int rest = idx >> 5;
  int n = rest & 2047; rest >>= 11; int t = rest & 15; int s = rest >> 4;
  const float* in = (s ? svcx : loadx) + ((size_t)t*N_E + n)*3;
  const float* W = s ? Wa : Wp; const float* b = s ? ba : bp;
  float acc = b[g];
  #pragma unroll
  for (int c=0;c<3;c++) acc += in[c]*W[g*3+c];
  (s ? x0a : x0p)[((size_t)t*N_E + n)*32 + g] = acc;
}

// ---------------- dilated causal conv (kernel 3) + ReLU, scaled by Zinv[n] ----------------
// y' = relu(conv(x)) * Zinv  (softmax denominator folded in here)
__global__ __launch_bounds__(256) void k_conv(const float* __restrict__ xp, const float* __restrict__ xa,
                       const float* __restrict__ Wtp, const float* __restrict__ Wta,
                       const float* __restrict__ btp, const float* __restrict__ bta,
                       const float* __restrict__ Zg,
                       float* __restrict__ yp, float* __restrict__ ya,
                       int layer, int dd, int tbase, int tstep) {
  __shared__ float sW[3*32*32];
  __shared__ float sX[8][3][32];
  int s = blockIdx.z;
  int t = tbase + blockIdx.y*tstep;
  const float* x  = s ? xa : xp;
  const float* Wt = (s ? Wta : Wtp) + (size_t)layer*3*32*32;
  const float* bt = (s ? bta : btp) + layer*32;
  float* y = s ? ya : yp;
  int tid = threadIdx.x;
  for (int i = tid; i < 3*32*32; i += 256) sW[i] = Wt[i];
  int n0 = blockIdx.x*8;
  for (int i = tid; i < 768; i += 256) {
    int f = i & 31; int nn = (i>>5)&7; int j = i >> 8;
    int tt = t - (2-j)*dd;
    sX[nn][j][f] = (tt >= 0) ? x[((size_t)tt*N_E + n0+nn)*32 + f] : 0.f;
  }
  __syncthreads();
  int g = tid & 31, nn = tid >> 5;
  float acc = bt[g];
  #pragma unroll
  for (int j=0;j<3;j++)
    #pragma unroll
    for (int f=0;f<32;f++) acc += sX[nn][j][f]*sW[(j*32+f)*32+g];
  float zi = Zg[((size_t)s*KT + t)*N_E + n0+nn];
  y[((size_t)t*N_E + n0+nn)*32 + g] = fmaxf(acc, 0.f)*zi;
}

// ---------------- ysum[s,ty,f] = sum_n y'[n,f] (f32 colsum of normalized y) ----------------
__global__ __launch_bounds__(256) void k_ysum(const float* __restrict__ yp, const float* __restrict__ ya,
                       float* __restrict__ ysumb, int tbase, int tstep, int nt) {
  __shared__ float red[256];
  int ty = blockIdx.x, s = blockIdx.y;
  int t = tbase + ty*tstep;
  const float* y = (s ? ya : yp) + (size_t)t*N_E*32;
  int tid = threadIdx.x;
  int f = tid & 31, sl = tid >> 5;
  float a = 0.f;
  for (int nn = sl*256; nn < sl*256 + 256; nn++) a += y[(size_t)nn*32 + f];
  red[tid] = a;
  __syncthreads();
  if (tid < 32) {
    float acc = 0.f;
    #pragma unroll
    for (int k=0;k<8;k++) acc += red[tid + 32*k];
    ysumb[((size_t)s*nt + ty)*32 + tid] = acc;
  }
}

// --------- MFMA mixing: part[m,f] = sum_n q[n,m] * y'[n,f],  q = expm1(relu(T[n].ep[m])) ---------
// out = colsum(y') + q-term; q fed to bf16 MFMA (16x16x32), f32 accumulate.
// MFMA layout assumptions (AMD matrix calculator, 16x16x32):
//   A[row][k]: row=lane%16, k=8*(lane/16)+elem ; B[k][col]: col=lane%16, k=8*(lane/16)+elem
//   D[row][col]: col=lane%16, row=4*(lane/16)+reg   (verified layout per guide m89)
__global__ __launch_bounds__(256) void k_mixm(const float* __restrict__ Tp, const float* __restrict__ Ta,
                      const float* __restrict__ epp, const float* __restrict__ epa,
                      const float* __restrict__ yp, const float* __restrict__ ya,
                      float* __restrict__ part,
                      int tbase, int tstep, int nt, int nsplit) {
  __shared__ float sT[128*8];     // 4 KiB
  __shared__ float sY[128*33];    // 16.9 KiB (pad 33: conflict-free column reads)
  int s = blockIdx.z, ty = blockIdx.y;
  int t = tbase + ty*tstep;
  int mtile = blockIdx.x & 31, split = blockIdx.x >> 5;
  int tid = threadIdx.x;
  int w = tid >> 6, lane = tid & 63;
  int g = lane >> 4, fc = lane & 15;
  int m0 = mtile*64 + w*16;
  const float* T  = (s ? Ta : Tp) + (size_t)t*N_E*8;
  const float* ep = (s ? epa : epp) + (size_t)t*N_E*8;
  const float* y  = (s ? ya : yp) + (size_t)t*N_E*32;
  float er[8];
  {
    const float4* gep = (const float4*)(ep + (size_t)(m0 + fc)*8);
    float4 a = gep[0], b = gep[1];
    er[0]=a.x; er[1]=a.y; er[2]=a.z; er[3]=a.w;
    er[4]=b.x; er[5]=b.y; er[6]=b.z; er[7]=b.w;
  }
  f32x4 acc0 = {0.f,0.f,0.f,0.f}, acc1 = {0.f,0.f,0.f,0.f};
  int n0 = split*(N_E/nsplit), n1 = n0 + (N_E/nsplit);
  for (int c0 = n0; c0 < n1; c0 += 128) {
    __syncthreads();
    {  // stage T chunk: 128x8 f32 = 256 float4, one per thread
      const float4* gt = (const float4*)(T + (size_t)c0*8);
      ((float4*)sT)[tid] = gt[tid];
      // stage Y chunk: 128x32 f32 -> padded [128][33]
      const float4* gy = (const float4*)(y + (size_t)c0*32);
      #pragma unroll
      for (int k = 0; k < 4; k++) {
        int i = tid + k*256;            // float4 index; nn = i>>3, fq = i&7
        float4 v = gy[i];
        float* dst = &sY[(i>>3)*33 + (i&7)*4];
        dst[0]=v.x; dst[1]=v.y; dst[2]=v.z; dst[3]=v.w;
      }
    }
    __syncthreads();
    #pragma unroll
    for (int sub = 0; sub < 4; sub++) {
      int nb = sub*32;
      short8 af, bf0, bf1;
      #pragma unroll
      for (int i=0;i<8;i++) {
        const float* trr = &sT[(nb + g*8 + i)*8];
        float d = trr[0]*er[0];
        #pragma unroll
        for (int v=1;v<8;v++) d = fmaf(trr[v], er[v], d);
        af[i] = f2bf(expm1t(fmaxf(d, 0.f)));
      }
      #pragma unroll
      for (int i=0;i<8;i++) {
        int row = (nb + g*8 + i)*33;
        bf0[i] = f2bf(sY[row + fc]);
        bf1[i] = f2bf(sY[row + 16 + fc]);
      }
      acc0 = __builtin_amdgcn_mfma_f32_16x16x32_bf16(af, bf0, acc0, 0, 0, 0);
      acc1 = __builtin_amdgcn_mfma_f32_16x16x32_bf16(af, bf1, acc1, 0, 0, 0);
    }
  }
  float* pb = part + (size_t)((s*nt + ty)*nsplit + split)*(N_E*32);
  #pragma unroll
  for (int r=0;r<4;r++) {
    pb[(size_t)(m0 + g*4 + r)*32 + fc]      = acc0[r];
    pb[(size_t)(m0 + g*4 + r)*32 + 16 + fc] = acc1[r];
  }
}

// ---------------- reduce nsplit partials + ysum + Wg + bias + ReLU ----------------
__global__ __launch_bounds__(256) void k_wg(const float* __restrict__ part,
                     const float* __restrict__ ysumb,
                     const float* __restrict__ Wgp, const float* __restrict__ Wga,
                     const float* __restrict__ bgp, const float* __restrict__ bga,
                     float* __restrict__ xop, float* __restrict__ xoa,
                     int layer, int tbase, int tstep, int nt, int nsplit) {
  __shared__ float sX[8*32];
  __shared__ float sWg[32*32];
  __shared__ float sBg[32];
  int s = blockIdx.z, ty = blockIdx.y;
  int t = tbase + ty*tstep;
  int m0 = blockIdx.x*8;
  const float* Wg = (s ? Wga : Wgp) + (size_t)layer*1024;
  const float* bg = (s ? bga : bgp) + layer*32;
  int tid = threadIdx.x;
  for (int i = tid; i < 1024; i += 256) sWg[i] = Wg[i];
  if (tid < 32) sBg[tid] = bg[tid];
  {
    int mm = tid >> 5, f = tid & 31;
    const float* p = part + (size_t)((s*nt + ty)*nsplit)*(N_E*32) + (size_t)(m0+mm)*32 + f;
    float a = ysumb[((size_t)s*nt + ty)*32 + f];
    for (int sp = 0; sp < nsplit; sp++) a += p[(size_t)sp*(N_E*32)];
    sX[mm*32+f] = a;
  }
  __syncthreads();
  int mm = tid >> 5, g = tid & 31;
  float a = sBg[g];
  #pragma unroll
  for (int f=0;f<32;f++) a += sX[mm*32+f]*sWg[f*32+g];
  (s ? xoa : xop)[((size_t)t*N_E + m0+mm)*32 + g] = fmaxf(a, 0.f);
}

// ---------------- fused gather + 6-layer MLP head ----------------
__global__ __launch_bounds__(64) void k_mlp(const int* __restrict__ info,
    const float* __restrict__ tf, const float* __restrict__ fpp, const float* __restrict__ fpa,
    const float* __restrict__ se, const float* __restrict__ ve,
    const float* __restrict__ W0, const float* __restrict__ b0,
    const float* __restrict__ W1, const float* __restrict__ b1,
    const float* __restrict__ W2, const float* __restrict__ b2,
    const float* __restrict__ W3, const float* __restrict__ b3,
    const float* __restrict__ W4, const float* __restrict__ b4,
    const float* __restrict__ W5, const float* __restrict__ b5,
    float* __restrict__ out) {
  int r = blockIdx.x*64 + threadIdx.x;
  int uid = info[r*4+0], eid = info[r*4+1], sid = info[r*4+2];
  float o0[64];
  #pragma unroll
  for (int g=0;g<64;g++) o0[g] = b0[g];
  for (int k=0;k<16;k++) {
    float v = tf[uid*16+k];
    #pragma unroll
    for (int g=0;g<64;g++) o0[g] = fmaf(W0[g*112+k], v, o0[g]);
  }
  for (int k=0;k<32;k++) {
    float v = 0.5f*(fpp[eid*32+k] + fpa[eid*32+k]);
    #pragma unroll
    for (int g=0;g<64;g++) o0[g] = fmaf(W0[g*112+16+k], v, o0[g]);
  }
  for (int k=0;k<32;k++) {
    float v = se[eid*32+k];
    #pragma unroll
    for (int g=0;g<64;g++) o0[g] = fmaf(W0[g*112+48+k], v, o0[g]);
  }
  for (int k=0;k<32;k++) {
    float v = ve[sid*32+k];
    #pragma unroll
    for (int g=0;g<64;g++) o0[g] = fmaf(W0[g*112+80+k], v, o0[g]);
  }
  #pragma unroll
  for (int g=0;g<64;g++) o0[g] = fmaxf(o0[g], 0.f);
  float o1[32];
  #pragma unroll
  for (int g=0;g<32;g++) {
    float a = b1[g];
    #pragma unroll
    for (int k=0;k<64;k++) a = fmaf(W1[g*64+k], o0[k], a);
    o1[g] = fmaxf(a, 0.f);
  }
  float o2[16];
  #pragma unroll
  for (int g=0;g<16;g++) {
    float a = b2[g];
    #pragma unroll
    for (int k=0;k<32;k++) a = fmaf(W2[g*32+k], o1[k], a);
    o2[g] = fmaxf(a, 0.f);
  }
  float o3[8];
  #pragma unroll
  for (int g=0;g<8;g++) {
    float a = b3[g];
    #pragma unroll
    for (int k=0;k<16;k++) a = fmaf(W3[g*16+k], o2[k], a);
    o3[g] = fmaxf(a, 0.f);
  }
  float o4[4];
  #pragma unroll
  for (int g=0;g<4;g++) {
    float a = b4[g];
    #pragma unroll
    for (int k=0;k<8;k++) a = fmaf(W4[g*8+k], o3[k], a);
    o4[g] = fmaxf(a, 0.f);
  }
  float o5 = b5[0];
  #pragma unroll
  for (int k=0;k<4;k++) o5 = fmaf(W5[k], o4[k], o5);
  out[r] = o5;
}

extern "C" void kernel_launch(void* const* d_in, const int* in_sizes, int n_in,
                              void* d_out, int out_size, void* d_ws, size_t ws_size,
                              hipStream_t stream) {
  (void)in_sizes; (void)n_in; (void)out_size;
  const float* edge    = (const float*)d_in[0];
  const float* loadx   = (const float*)d_in[1];
  const float* svcx    = (const float*)d_in[2];
  const float* tra     = (const float*)d_in[3];
  const int*   info    = (const int*)d_in[4];
  const int*   srv_attr= (const int*)d_in[5];
  const int*   svc_attr= (const int*)d_in[6];
  const float* usr_tab = (const float*)d_in[7];
  const float* srv_tab0= (const float*)d_in[8];
  const float* srv_lvl = (const float*)d_in[9];
  const float* svc_tab0= (const float*)d_in[10];
  const float* svc_lvl = (const float*)d_in[11];
  const float* Wih = (const float*)d_in[12];
  const float* Whh = (const float*)d_in[13];
  const float* bih = (const float*)d_in[14];
  const float* bhh = (const float*)d_in[15];
  const float* E1p = (const float*)d_in[16];
  const float* E2p = (const float*)d_in[17];
  const float* peWp= (const float*)d_in[18];
  const float* pebp= (const float*)d_in[19];
  const float* E1a = (const float*)d_in[20];
  const float* E2a = (const float*)d_in[21];
  const float* peWa= (const float*)d_in[22];
  const float* peba= (const float*)d_in[23];
  const float* prWp= (const float*)d_in[24];
  const float* prbp= (const float*)d_in[25];
  const float* prWa= (const float*)d_in[26];
  const float* prba= (const float*)d_in[27];
  const float* Wtp = (const float*)d_in[28];
  const float* btp = (const float*)d_in[29];
  const float* Wgp = (const float*)d_in[30];
  const float* bgp = (const float*)d_in[31];
  const float* Wta = (const float*)d_in[32];
  const float* bta = (const float*)d_in[33];
  const float* Wga = (const float*)d_in[34];
  const float* bga = (const float*)d_in[35];
  const float* qW0 = (const float*)d_in[36]; const float* qb0 = (const float*)d_in[37];
  const float* qW1 = (const float*)d_in[38]; const float* qb1 = (const float*)d_in[39];
  const float* qW2 = (const float*)d_in[40]; const float* qb2 = (const float*)d_in[41];
  const float* qW3 = (const float*)d_in[42]; const float* qb3 = (const float*)d_in[43];
  const float* qW4 = (const float*)d_in[44]; const float* qb4 = (const float*)d_in[45];
  const float* qW5 = (const float*)d_in[46]; const float* qb5 = (const float*)d_in[47];
  float* out = (float*)d_out;

  // workspace layout (floats); part sized from remaining ws
  float* ws = (float*)d_ws;
  size_t off = 0;
  float* srv_emb  = ws + off; off += (size_t)N_E*32;
  float* svc_emb  = ws + off; off += (size_t)N_SVC*32;
  float* tra_feat = ws + off; off += (size_t)N_U*16;
  float* epb      = ws + off; off += 2ull*KT*N_E*8;     // [s][t][n][8]
  float* Tb       = ws + off; off += 2ull*KT*N_E*8;
  float* Zb       = ws + off; off += 2ull*KT*N_E;       // 1/softmax-denominator
  float* ysumb    = ws + off; off += 2ull*KT*32;        // per-(s,t) colsum of y'
  float* x0b      = ws + off; off += 2ull*STRX;
  float* xAb      = ws + off; off += 2ull*STRX;
  float* yb       = ws + off; off += 2ull*STRX;
  float* part     = ws + off;                           // rest of ws

  size_t slab = (size_t)N_E*32;                          // 65536 floats
  size_t avail_floats = (ws_size/4 > off) ? (ws_size/4 - off) : 0;
  int cap = (int)(avail_floats / slab);                  // total part slabs available

  float* epp = epb;              float* epa = epb + (size_t)KT*N_E*8;
  float* Tp  = Tb;               float* Ta  = Tb  + (size_t)KT*N_E*8;
  // stats partials alias onto `part`: consumed by k_zinv before first k_mixm writes it
  float* partC = part;           // needs 8 slabs (2 MB)

  k_embed<<<384,256,0,stream>>>(srv_attr, svc_attr, srv_tab0, srv_lvl, svc_tab0, svc_lvl, srv_emb, svc_emb);
  k_lstm <<<256,256,0,stream>>>(usr_tab, tra, Wih, Whh, bih, bhh, tra_feat);
  k_pe   <<<2048,256,0,stream>>>(edge, peWp, pebp, peWa, peba, epp, epa);
  k_T    <<<32,256,0,stream>>>(epp, epa, E1p, E2p, E1a, E2a, Tp, Ta);
  k_stats<<<dim3(64,16,2),256,0,stream>>>(Tp, Ta, epp, epa, partC);
  k_zinv <<<256,256,0,stream>>>(partC, Zb);
  k_proj <<<8192,256,0,stream>>>(loadx, svcx, prWp, prbp, prWa, prba, x0b, x0b + STRX);

  // per-layer active time sets (backward-propagated from t=15 output)
  const int Ldd[4]   = {1, 2, 1, 2};
  const int Ltb[4]   = {5, 9, 11, 15};
  const int Lts[4]   = {1, 1, 2, 1};
  const int Lnt[4]   = {11, 7, 3, 1};
  int Lsp[4]         = {4, 4, 8, 16};        // n-splits (occupancy vs part traffic)
  for (int i = 0; i < 4; i++)
    while (Lsp[i] > 1 && 2*Lnt[i]*Lsp[i] > cap) Lsp[i] >>= 1;

  float* xin = x0b;
  float* xout = xAb;
  for (int i = 0; i < 4; i++) {
    k_conv<<<dim3(256, Lnt[i], 2), 256, 0, stream>>>(
        xin, xin + STRX, Wtp, Wta, btp, bta, Zb, yb, yb + STRX, i, Ldd[i], Ltb[i], Lts[i]);
    k_ysum<<<dim3(Lnt[i], 2), 256, 0, stream>>>(yb, yb + STRX, ysumb, Ltb[i], Lts[i], Lnt[i]);
    k_mixm<<<dim3(32*Lsp[i], Lnt[i], 2), 256, 0, stream>>>(
        Tp, Ta, epp, epa, yb, yb + STRX, part, Ltb[i], Lts[i], Lnt[i], Lsp[i]);
    k_wg<<<dim3(256, Lnt[i], 2), 256, 0, stream>>>(
        part, ysumb, Wgp, Wga, bgp, bga, xout, xout + STRX, i, Ltb[i], Lts[i], Lnt[i], Lsp[i]);
    float* tmp = xin; xin = xout; xout = tmp;
  }
  // final stream features at t=15 live in xin
  const float* fpp = xin + (size_t)15*N_E*32;
  const float* fpa = xin + STRX + (size_t)15*N_E*32;

  k_mlp<<<128,64,0,stream>>>(info, tra_feat, fpp, fpa, srv_emb, svc_emb,
                             qW0, qb0, qW1, qb1, qW2, qb2, qW3, qb3, qW4, qb4, qW5, qb5, out);
}

// Round 5
// 589.558 us; speedup vs baseline: 1.3848x; 1.3848x over previous
//
#include <hip/hip_runtime.h>
#include <math.h>

#define N_E 2048
#define N_U 4096
#define N_SVC 1024
#define KT 16
#define STRX (KT*N_E*32)   // per-stream x/y buffer stride (floats)

typedef __attribute__((ext_vector_type(8))) short short8;   // 8 bf16 (4 VGPRs)
typedef __attribute__((ext_vector_type(4))) float f32x4;

__device__ __forceinline__ float sigf(float x){ return 1.0f/(1.0f+__expf(-x)); }
__device__ __forceinline__ float tanhfast(float x){ return 1.0f - 2.0f/(__expf(2.0f*x)+1.0f); }
__device__ __forceinline__ short f2bf(float f){
  union { float f; unsigned u; } x; x.f = f;
  unsigned r = x.u + 0x7FFFu + ((x.u >> 16) & 1u);
  return (short)(r >> 16);
}
// expm1 via 4-term Taylor: rel err <1e-5 for d in [0, 0.5]; d here is ~<0.05
__device__ __forceinline__ float expm1t(float d){
  float t = fmaf(d, 1.f/24.f, 1.f/6.f);
  t = fmaf(d, t, 0.5f);
  t = fmaf(d, t, 1.f);
  return d*t;
}

// ---------------- embeddings: srv_emb (2048x32), svc_emb (1024x32) ----------------
__global__ void k_embed(const int* __restrict__ srv_attr, const int* __restrict__ svc_attr,
                        const float* __restrict__ srv_tab0, const float* __restrict__ srv_lvl,
                        const float* __restrict__ svc_tab0, const float* __restrict__ svc_lvl,
                        float* __restrict__ srv_emb, float* __restrict__ svc_emb) {
  int idx = blockIdx.x*256 + threadIdx.x;       // (2048+1024) rows * 32 cols
  int r = idx >> 5, c = idx & 31;
  int seg = c >> 3, cc = c & 7;
  if (r < N_E) {
    int a = srv_attr[r*4 + seg];
    srv_emb[r*32 + c] = (seg==0) ? srv_tab0[a*8+cc] : srv_lvl[((seg-1)*10 + a)*8 + cc];
  } else {
    int r2 = r - N_E;
    if (r2 < N_SVC) {
      int a = svc_attr[r2*4 + seg];
      svc_emb[r2*32 + c] = (seg==0) ? svc_tab0[a*8+cc] : svc_lvl[((seg-1)*10 + a)*8 + cc];
    }
  }
}

// ---------------- LSTM: 16 lanes per user, lane j owns hidden unit j ----------------
__global__ __launch_bounds__(256) void k_lstm(const float* __restrict__ usr_tab, const float* __restrict__ tra,
                       const float* __restrict__ Wih, const float* __restrict__ Whh,
                       const float* __restrict__ bih, const float* __restrict__ bhh,
                       float* __restrict__ tra_feat) {
  __shared__ float sWih[64*12];
  __shared__ float sWhh[64*16];
  __shared__ float sB[64];
  int tid = threadIdx.x;
  for (int i = tid; i < 64*12; i += 256) sWih[i] = Wih[i];
  for (int i = tid; i < 64*16; i += 256) sWhh[i] = Whh[i];
  if (tid < 64) sB[tid] = bih[tid] + bhh[tid];
  __syncthreads();
  int j  = tid & 15;
  int u  = blockIdx.x*16 + (tid >> 4);
  float xe[8];
  #pragma unroll
  for (int k=0;k<8;k++) xe[k] = usr_tab[u*8+k];
  float h = 0.f, c = 0.f;
  for (int t=0;t<KT;t++) {
    float gi = sB[j], gf = sB[16+j], gg = sB[32+j], go = sB[48+j];
    #pragma unroll
    for (int k=0;k<8;k++) {
      float v = xe[k];
      gi += sWih[j*12+k]*v;      gf += sWih[(16+j)*12+k]*v;
      gg += sWih[(32+j)*12+k]*v; go += sWih[(48+j)*12+k]*v;
    }
    #pragma unroll
    for (int k=0;k<4;k++) {
      float v = tra[((size_t)t*N_U + u)*4 + k];
      gi += sWih[j*12+8+k]*v;      gf += sWih[(16+j)*12+8+k]*v;
      gg += sWih[(32+j)*12+8+k]*v; go += sWih[(48+j)*12+8+k]*v;
    }
    #pragma unroll
    for (int jj=0;jj<16;jj++) {
      float hv = __shfl(h, jj, 16);
      gi += sWhh[j*16+jj]*hv;      gf += sWhh[(16+j)*16+jj]*hv;
      gg += sWhh[(32+j)*16+jj]*hv; go += sWhh[(48+j)*16+jj]*hv;
    }
    c = sigf(gf)*c + sigf(gi)*tanhfast(gg);
    h = sigf(go)*tanhfast(c);
  }
  tra_feat[u*16 + j] = h;
}

// ---------------- ep/ea = edge @ peW^T + b : only t in [5,15] ----------------
__global__ void k_pe(const float* __restrict__ edge,
                     const float* __restrict__ Wp, const float* __restrict__ bp,
                     const float* __restrict__ Wa, const float* __restrict__ ba,
                     float* __restrict__ ep, float* __restrict__ ea) {
  int idx = blockIdx.x*256 + threadIdx.x;        // s(2)*t(11)*n(2048)*c(8) = 360448
  int c = idx & 7; int rest = idx >> 3;
  int n = rest & 2047; rest >>= 11;              // rest in [0, 22)
  int t = 5 + (rest % 11); int s = rest / 11;
  const float* W = s ? Wa : Wp; const float* b = s ? ba : bp;
  const float* e = edge + ((size_t)t*N_E + n)*11;
  float acc = b[c];
  #pragma unroll
  for (int k=0;k<11;k++) acc += e[k]*W[c*11+k];
  (s ? ea : ep)[((size_t)t*N_E + n)*8 + c] = acc;
}

// ---------------- T[t] = ep[t] @ (E2[t] . E1) : only t in [5,15] ----------------
__global__ void k_T(const float* __restrict__ epp, const float* __restrict__ epa,
                    const float* __restrict__ E1p, const float* __restrict__ E2p,
                    const float* __restrict__ E1a, const float* __restrict__ E2a,
                    float* __restrict__ Tp, float* __restrict__ Ta) {
  __shared__ float sM[64];
  int s = blockIdx.x / 11, t = 5 + blockIdx.x % 11;
  const float* E1 = s ? E1a : E1p;
  const float* E2 = s ? E2a : E2p;
  const float* ep = (s ? epa : epp) + (size_t)t*N_E*8;
  float* T = (s ? Ta : Tp) + (size_t)t*N_E*8;
  int tid = threadIdx.x;
  if (tid < 64) {
    int u = tid >> 3, v = tid & 7;
    float m = 0.f;
    #pragma unroll
    for (int o=0;o<8;o++) m += E2[t*8+o]*E1[(o*8+u)*8+v];
    sM[u*8+v] = m;
  }
  __syncthreads();
  for (int e2 = tid; e2 < N_E*8; e2 += 256) {
    int i = e2 >> 3, v = e2 & 7;
    float acc = 0.f;
    #pragma unroll
    for (int u=0;u<8;u++) acc += ep[i*8+u]*sM[u*8+v];
    T[e2] = acc;
  }
}

// --------- softmax row partials: partC[s,t,sp,n] = sum_{m in split sp} exp(relu(T[n].ep[m])) ---------
__global__ __launch_bounds__(256) void k_stats(const float* __restrict__ Tp, const float* __restrict__ Ta,
                        const float* __restrict__ epp, const float* __restrict__ epa,
                        float* __restrict__ partC) {
  __shared__ float sE[256*8];   // 8 KiB
  int s = blockIdx.z, t = 5 + blockIdx.y;
  int ntile = blockIdx.x & 7, sp = blockIdx.x >> 3;
  int n = ntile*256 + threadIdx.x;
  const float* T = (s ? Ta : Tp) + ((size_t)t*N_E + n)*8;
  const float* E = (s ? epa : epp) + (size_t)t*N_E*8;
  int tid = threadIdx.x;
  float tr[8];
  {
    const float4* gt = (const float4*)T;
    float4 a = gt[0], b = gt[1];
    tr[0]=a.x; tr[1]=a.y; tr[2]=a.z; tr[3]=a.w;
    tr[4]=b.x; tr[5]=b.y; tr[6]=b.z; tr[7]=b.w;
  }
  int m0 = sp*256;
  {
    const float4* ge = (const float4*)(E + (size_t)m0*8);
    float4* se = (float4*)sE;
    for (int i = tid; i < 512; i += 256) se[i] = ge[i];
  }
  __syncthreads();
  float psum = 0.f;
  #pragma unroll 4
  for (int m = 0; m < 256; m++) {
    float d = 0.f;
    #pragma unroll
    for (int v=0;v<8;v++) d = fmaf(sE[m*8+v], tr[v], d);
    psum += __expf(fmaxf(d, 0.f));
  }
  partC[(((size_t)s*KT + t)*8 + sp)*N_E + n] = psum;
}

// ---------------- Zinv = 1 / (sum of 8 partials), t in [5,15] ----------------
__global__ void k_zinv(const float* __restrict__ partC, float* __restrict__ Z) {
  int i = blockIdx.x*256 + threadIdx.x;   // 2*11*2048 = 45056
  int n = i & 2047; int stp = i >> 11;    // [0,22)
  int s = stp / 11, t = 5 + stp % 11;
  float a = 0.f;
  #pragma unroll
  for (int sp=0;sp<8;sp++) a += partC[(((size_t)s*KT + t)*8 + sp)*N_E + n];
  Z[((size_t)s*KT + t)*N_E + n] = 1.0f/a;
}

// ---------------- x0 = proj(load / svc_tot) : (16,2048,32) x2 ----------------
__global__ void k_proj(const float* __restrict__ loadx, const float* __restrict__ svcx,
                       const float* __restrict__ Wp, const float* __restrict__ bp,
                       const float* __restrict__ Wa, const float* __restrict__ ba,
                       float* __restrict__ x0p, float* __restrict__ x0a) {
  int idx = blockIdx.x*256 + threadIdx.x;        // s t n g : 21 bits
  int g = idx & 31; int rest = idx >> 5;
  int n = rest & 2047; rest >>= 11; int t = rest & 15; int s = rest >> 4;
  const float* in = (s ? svcx : loadx) + ((size_t)t*N_E + n)*3;
  const float* W = s ? Wa : Wp; const float* b = s ? ba : bp;
  float acc = b[g];
  #pragma unroll
  for (int c=0;c<3;c++) acc += in[c]*W[g*3+c];
  (s ? x0a : x0p)[((size_t)t*N_E + n)*32 + g] = acc;
}

// ---------------- dilated causal conv (kernel 3) + ReLU, scaled by Zinv[n] ----------------
__global__ __launch_bounds__(256) void k_conv(const float* __restrict__ xp, const float* __restrict__ xa,
                       const float* __restrict__ Wtp, const float* __restrict__ Wta,
                       const float* __restrict__ btp, const float* __restrict__ bta,
                       const float* __restrict__ Zg,
                       float* __restrict__ yp, float* __restrict__ ya,
                       int layer, int dd, int tbase, int tstep) {
  __shared__ float sW[3*32*32];
  __shared__ float sX[8][3][32];
  int s = blockIdx.z;
  int t = tbase + blockIdx.y*tstep;
  const float* x  = s ? xa : xp;
  const float* Wt = (s ? Wta : Wtp) + (size_t)layer*3*32*32;
  const float* bt = (s ? bta : btp) + layer*32;
  float* y = s ? ya : yp;
  int tid = threadIdx.x;
  for (int i = tid; i < 3*32*32; i += 256) sW[i] = Wt[i];
  int n0 = blockIdx.x*8;
  for (int i = tid; i < 768; i += 256) {
    int f = i & 31; int nn = (i>>5)&7; int j = i >> 8;
    int tt = t - (2-j)*dd;
    sX[nn][j][f] = (tt >= 0) ? x[((size_t)tt*N_E + n0+nn)*32 + f] : 0.f;
  }
  __syncthreads();
  int g = tid & 31, nn = tid >> 5;
  float acc = bt[g];
  #pragma unroll
  for (int j=0;j<3;j++)
    #pragma unroll
    for (int f=0;f<32;f++) acc += sX[nn][j][f]*sW[(j*32+f)*32+g];
  float zi = Zg[((size_t)s*KT + t)*N_E + n0+nn];
  y[((size_t)t*N_E + n0+nn)*32 + g] = fmaxf(acc, 0.f)*zi;
}

// ---------------- ysum[s,ty,f] = sum_n y'[n,f] (f32 colsum of normalized y) ----------------
__global__ __launch_bounds__(256) void k_ysum(const float* __restrict__ yp, const float* __restrict__ ya,
                       float* __restrict__ ysumb, int tbase, int tstep, int nt) {
  __shared__ f32x4 red[256];
  int ty = blockIdx.x, s = blockIdx.y;
  int t = tbase + ty*tstep;
  const float4* y = (const float4*)((s ? ya : yp) + (size_t)t*N_E*32);
  int tid = threadIdx.x;
  f32x4 a = {0.f,0.f,0.f,0.f};
  for (int i = tid; i < N_E*8; i += 256) {   // i mod 8 == tid mod 8: fixed f-quad per thread
    float4 v = y[i];
    a[0]+=v.x; a[1]+=v.y; a[2]+=v.z; a[3]+=v.w;
  }
  red[tid] = a;
  __syncthreads();
  if (tid < 32) {
    int q = tid >> 2, c = tid & 3;
    float acc = 0.f;
    #pragma unroll 8
    for (int j=0;j<32;j++) acc += red[q + 8*j][c];
    ysumb[((size_t)s*nt + ty)*32 + tid] = acc;
  }
}

// --------- MFMA mixing: part[m,f] = sum_n q[n,m] * y'[n,f],  q = expm1(relu(T[n].ep[m])) ---------
// out = colsum(y') + q-term.  LDS: T transposed [8][136] (conflict-free b128 broadcast reads),
// y' pre-converted bf16 [128][34] (u16 reads, word-pair sharing = free).
__global__ __launch_bounds__(256) void k_mixm(const float* __restrict__ Tp, const float* __restrict__ Ta,
                      const float* __restrict__ epp, const float* __restrict__ epa,
                      const float* __restrict__ yp, const float* __restrict__ ya,
                      float* __restrict__ part,
                      int tbase, int tstep, int nt, int nsplit) {
  __shared__ float sTt[8*136];    // 4.25 KiB, T^T padded
  __shared__ short sYb[128*34];   // 8.5 KiB, y' bf16 padded
  int s = blockIdx.z, ty = blockIdx.y;
  int t = tbase + ty*tstep;
  int mtile = blockIdx.x & 31, split = blockIdx.x >> 5;
  int tid = threadIdx.x;
  int w = tid >> 6, lane = tid & 63;
  int g = lane >> 4, fc = lane & 15;
  int m0 = mtile*64 + w*16;
  const float* T  = (s ? Ta : Tp) + (size_t)t*N_E*8;
  const float* ep = (s ? epa : epp) + (size_t)t*N_E*8;
  const float* y  = (s ? ya : yp) + (size_t)t*N_E*32;
  float er[8];
  {
    const float4* gep = (const float4*)(ep + (size_t)(m0 + fc)*8);
    float4 a = gep[0], b = gep[1];
    er[0]=a.x; er[1]=a.y; er[2]=a.z; er[3]=a.w;
    er[4]=b.x; er[5]=b.y; er[6]=b.z; er[7]=b.w;
  }
  f32x4 acc0 = {0.f,0.f,0.f,0.f}, acc1 = {0.f,0.f,0.f,0.f};
  int n0 = split*(N_E/nsplit), n1 = n0 + (N_E/nsplit);   // multiples of 128 always
  for (int c0 = n0; c0 < n1; c0 += 128) {
    __syncthreads();
    {  // stage T transposed: 128x8 f32 = 256 float4, one per thread
      const float4* gt = (const float4*)(T + (size_t)c0*8);
      float4 v = gt[tid];
      int r = tid >> 1, vb = (tid & 1)*4;
      sTt[(vb+0)*136 + r] = v.x; sTt[(vb+1)*136 + r] = v.y;
      sTt[(vb+2)*136 + r] = v.z; sTt[(vb+3)*136 + r] = v.w;
      // stage Y chunk as bf16: 128x32
      const float* gy = y + (size_t)c0*32;
      for (int i = tid; i < 4096; i += 256)
        sYb[(i>>5)*34 + (i&31)] = f2bf(gy[i]);
    }
    __syncthreads();
    #pragma unroll
    for (int sub = 0; sub < 4; sub++) {
      int rbase = sub*32 + g*8;
      f32x4 dA = {0.f,0.f,0.f,0.f}, dB = {0.f,0.f,0.f,0.f};
      #pragma unroll
      for (int v=0; v<8; v++) {
        const f32x4* tv = (const f32x4*)&sTt[v*136 + rbase];  // 16B-aligned
        f32x4 ta = tv[0], tb = tv[1];
        float e = er[v];
        dA += ta * e;
        dB += tb * e;
      }
      short8 af;
      #pragma unroll
      for (int i=0;i<4;i++) af[i]   = f2bf(expm1t(fmaxf(dA[i], 0.f)));
      #pragma unroll
      for (int i=0;i<4;i++) af[4+i] = f2bf(expm1t(fmaxf(dB[i], 0.f)));
      short8 bf0, bf1;
      #pragma unroll
      for (int i=0;i<8;i++) {
        int row = (rbase + i)*34;
        bf0[i] = sYb[row + fc];
        bf1[i] = sYb[row + 16 + fc];
      }
      acc0 = __builtin_amdgcn_mfma_f32_16x16x32_bf16(af, bf0, acc0, 0, 0, 0);
      acc1 = __builtin_amdgcn_mfma_f32_16x16x32_bf16(af, bf1, acc1, 0, 0, 0);
    }
  }
  float* pb = part + (size_t)((s*nt + ty)*nsplit + split)*(N_E*32);
  #pragma unroll
  for (int r=0;r<4;r++) {
    pb[(size_t)(m0 + g*4 + r)*32 + fc]      = acc0[r];
    pb[(size_t)(m0 + g*4 + r)*32 + 16 + fc] = acc1[r];
  }
}

// ---------------- reduce nsplit partials + ysum + Wg + bias + ReLU ----------------
__global__ __launch_bounds__(256) void k_wg(const float* __restrict__ part,
                     const float* __restrict__ ysumb,
                     const float* __restrict__ Wgp, const float* __restrict__ Wga,
                     const float* __restrict__ bgp, const float* __restrict__ bga,
                     float* __restrict__ xop, float* __restrict__ xoa,
                     int layer, int tbase, int tstep, int nt, int nsplit) {
  __shared__ float sX[8*32];
  __shared__ float sWg[32*32];
  __shared__ float sBg[32];
  int s = blockIdx.z, ty = blockIdx.y;
  int t = tbase + ty*tstep;
  int m0 = blockIdx.x*8;
  const float* Wg = (s ? Wga : Wgp) + (size_t)layer*1024;
  const float* bg = (s ? bga : bgp) + layer*32;
  int tid = threadIdx.x;
  for (int i = tid; i < 1024; i += 256) sWg[i] = Wg[i];
  if (tid < 32) sBg[tid] = bg[tid];
  {
    int mm = tid >> 5, f = tid & 31;
    const float* p = part + (size_t)((s*nt + ty)*nsplit)*(N_E*32) + (size_t)(m0+mm)*32 + f;
    float a = ysumb[((size_t)s*nt + ty)*32 + f];
    for (int sp = 0; sp < nsplit; sp++) a += p[(size_t)sp*(N_E*32)];
    sX[mm*32+f] = a;
  }
  __syncthreads();
  int mm = tid >> 5, g = tid & 31;
  float a = sBg[g];
  #pragma unroll
  for (int f=0;f<32;f++) a += sX[mm*32+f]*sWg[f*32+g];
  (s ? xoa : xop)[((size_t)t*N_E + m0+mm)*32 + g] = fmaxf(a, 0.f);
}

// ---------------- fused gather + 6-layer MLP head ----------------
__global__ __launch_bounds__(64) void k_mlp(const int* __restrict__ info,
    const float* __restrict__ tf, const float* __restrict__ fpp, const float* __restrict__ fpa,
    const float* __restrict__ se, const float* __restrict__ ve,
    const float* __restrict__ W0, const float* __restrict__ b0,
    const float* __restrict__ W1, const float* __restrict__ b1,
    const float* __restrict__ W2, const float* __restrict__ b2,
    const float* __restrict__ W3, const float* __restrict__ b3,
    const float* __restrict__ W4, const float* __restrict__ b4,
    const float* __restrict__ W5, const float* __restrict__ b5,
    float* __restrict__ out) {
  int r = blockIdx.x*64 + threadIdx.x;
  int uid = info[r*4+0], eid = info[r*4+1], sid = info[r*4+2];
  float o0[64];
  #pragma unroll
  for (int g=0;g<64;g++) o0[g] = b0[g];
  for (int k=0;k<16;k++) {
    float v = tf[uid*16+k];
    #pragma unroll
    for (int g=0;g<64;g++) o0[g] = fmaf(W0[g*112+k], v, o0[g]);
  }
  for (int k=0;k<32;k++) {
    float v = 0.5f*(fpp[eid*32+k] + fpa[eid*32+k]);
    #pragma unroll
    for (int g=0;g<64;g++) o0[g] = fmaf(W0[g*112+16+k], v, o0[g]);
  }
  for (int k=0;k<32;k++) {
    float v = se[eid*32+k];
    #pragma unroll
    for (int g=0;g<64;g++) o0[g] = fmaf(W0[g*112+48+k], v, o0[g]);
  }
  for (int k=0;k<32;k++) {
    float v = ve[sid*32+k];
    #pragma unroll
    for (int g=0;g<64;g++) o0[g] = fmaf(W0[g*112+80+k], v, o0[g]);
  }
  #pragma unroll
  for (int g=0;g<64;g++) o0[g] = fmaxf(o0[g], 0.f);
  float o1[32];
  #pragma unroll
  for (int g=0;g<32;g++) {
    float a = b1[g];
    #pragma unroll
    for (int k=0;k<64;k++) a = fmaf(W1[g*64+k], o0[k], a);
    o1[g] = fmaxf(a, 0.f);
  }
  float o2[16];
  #pragma unroll
  for (int g=0;g<16;g++) {
    float a = b2[g];
    #pragma unroll
    for (int k=0;k<32;k++) a = fmaf(W2[g*32+k], o1[k], a);
    o2[g] = fmaxf(a, 0.f);
  }
  float o3[8];
  #pragma unroll
  for (int g=0;g<8;g++) {
    float a = b3[g];
    #pragma unroll
    for (int k=0;k<16;k++) a = fmaf(W3[g*16+k], o2[k], a);
    o3[g] = fmaxf(a, 0.f);
  }
  float o4[4];
  #pragma unroll
  for (int g=0;g<4;g++) {
    float a = b4[g];
    #pragma unroll
    for (int k=0;k<8;k++) a = fmaf(W4[g*8+k], o3[k], a);
    o4[g] = fmaxf(a, 0.f);
  }
  float o5 = b5[0];
  #pragma unroll
  for (int k=0;k<4;k++) o5 = fmaf(W5[k], o4[k], o5);
  out[r] = o5;
}

extern "C" void kernel_launch(void* const* d_in, const int* in_sizes, int n_in,
                              void* d_out, int out_size, void* d_ws, size_t ws_size,
                              hipStream_t stream) {
  (void)in_sizes; (void)n_in; (void)out_size;
  const float* edge    = (const float*)d_in[0];
  const float* loadx   = (const float*)d_in[1];
  const float* svcx    = (const float*)d_in[2];
  const float* tra     = (const float*)d_in[3];
  const int*   info    = (const int*)d_in[4];
  const int*   srv_attr= (const int*)d_in[5];
  const int*   svc_attr= (const int*)d_in[6];
  const float* usr_tab = (const float*)d_in[7];
  const float* srv_tab0= (const float*)d_in[8];
  const float* srv_lvl = (const float*)d_in[9];
  const float* svc_tab0= (const float*)d_in[10];
  const float* svc_lvl = (const float*)d_in[11];
  const float* Wih = (const float*)d_in[12];
  const float* Whh = (const float*)d_in[13];
  const float* bih = (const float*)d_in[14];
  const float* bhh = (const float*)d_in[15];
  const float* E1p = (const float*)d_in[16];
  const float* E2p = (const float*)d_in[17];
  const float* peWp= (const float*)d_in[18];
  const float* pebp= (const float*)d_in[19];
  const float* E1a = (const float*)d_in[20];
  const float* E2a = (const float*)d_in[21];
  const float* peWa= (const float*)d_in[22];
  const float* peba= (const float*)d_in[23];
  const float* prWp= (const float*)d_in[24];
  const float* prbp= (const float*)d_in[25];
  const float* prWa= (const float*)d_in[26];
  const float* prba= (const float*)d_in[27];
  const float* Wtp = (const float*)d_in[28];
  const float* btp = (const float*)d_in[29];
  const float* Wgp = (const float*)d_in[30];
  const float* bgp = (const float*)d_in[31];
  const float* Wta = (const float*)d_in[32];
  const float* bta = (const float*)d_in[33];
  const float* Wga = (const float*)d_in[34];
  const float* bga = (const float*)d_in[35];
  const float* qW0 = (const float*)d_in[36]; const float* qb0 = (const float*)d_in[37];
  const float* qW1 = (const float*)d_in[38]; const float* qb1 = (const float*)d_in[39];
  const float* qW2 = (const float*)d_in[40]; const float* qb2 = (const float*)d_in[41];
  const float* qW3 = (const float*)d_in[42]; const float* qb3 = (const float*)d_in[43];
  const float* qW4 = (const float*)d_in[44]; const float* qb4 = (const float*)d_in[45];
  const float* qW5 = (const float*)d_in[46]; const float* qb5 = (const float*)d_in[47];
  float* out = (float*)d_out;

  // workspace layout (floats); part sized from remaining ws
  float* ws = (float*)d_ws;
  size_t off = 0;
  float* srv_emb  = ws + off; off += (size_t)N_E*32;
  float* svc_emb  = ws + off; off += (size_t)N_SVC*32;
  float* tra_feat = ws + off; off += (size_t)N_U*16;
  float* epb      = ws + off; off += 2ull*KT*N_E*8;     // [s][t][n][8]
  float* Tb       = ws + off; off += 2ull*KT*N_E*8;
  float* Zb       = ws + off; off += 2ull*KT*N_E;       // 1/softmax-denominator
  float* ysumb    = ws + off; off += 2ull*KT*32;        // per-(s,t) colsum of y'
  float* x0b      = ws + off; off += 2ull*STRX;
  float* xAb      = ws + off; off += 2ull*STRX;
  float* yb       = ws + off; off += 2ull*STRX;
  float* part     = ws + off;                           // rest of ws

  size_t slab = (size_t)N_E*32;                          // 65536 floats
  size_t avail_floats = (ws_size/4 > off) ? (ws_size/4 - off) : 0;
  int cap = (int)(avail_floats / slab);                  // total part slabs available

  float* epp = epb;              float* epa = epb + (size_t)KT*N_E*8;
  float* Tp  = Tb;               float* Ta  = Tb  + (size_t)KT*N_E*8;
  // stats partials alias onto `part`: consumed by k_zinv before first k_mixm writes it
  float* partC = part;           // needs 8 slabs (2 MB)

  k_embed<<<384,256,0,stream>>>(srv_attr, svc_attr, srv_tab0, srv_lvl, svc_tab0, svc_lvl, srv_emb, svc_emb);
  k_lstm <<<256,256,0,stream>>>(usr_tab, tra, Wih, Whh, bih, bhh, tra_feat);
  k_pe   <<<1408,256,0,stream>>>(edge, peWp, pebp, peWa, peba, epp, epa);
  k_T    <<<22,256,0,stream>>>(epp, epa, E1p, E2p, E1a, E2a, Tp, Ta);
  k_stats<<<dim3(64,11,2),256,0,stream>>>(Tp, Ta, epp, epa, partC);
  k_zinv <<<176,256,0,stream>>>(partC, Zb);
  k_proj <<<8192,256,0,stream>>>(loadx, svcx, prWp, prbp, prWa, prba, x0b, x0b + STRX);

  // per-layer active time sets (backward-propagated from t=15 output)
  const int Ldd[4]   = {1, 2, 1, 2};
  const int Ltb[4]   = {5, 9, 11, 15};
  const int Lts[4]   = {1, 1, 2, 1};
  const int Lnt[4]   = {11, 7, 3, 1};
  int Lsp[4]         = {4, 4, 8, 16};        // n-splits (occupancy vs part traffic)
  for (int i = 0; i < 4; i++)
    while (Lsp[i] > 1 && 2*Lnt[i]*Lsp[i] > cap) Lsp[i] >>= 1;

  float* xin = x0b;
  float* xout = xAb;
  for (int i = 0; i < 4; i++) {
    k_conv<<<dim3(256, Lnt[i], 2), 256, 0, stream>>>(
        xin, xin + STRX, Wtp, Wta, btp, bta, Zb, yb, yb + STRX, i, Ldd[i], Ltb[i], Lts[i]);
    k_ysum<<<dim3(Lnt[i], 2), 256, 0, stream>>>(yb, yb + STRX, ysumb, Ltb[i], Lts[i], Lnt[i]);
    k_mixm<<<dim3(32*Lsp[i], Lnt[i], 2), 256, 0, stream>>>(
        Tp, Ta, epp, epa, yb, yb + STRX, part, Ltb[i], Lts[i], Lnt[i], Lsp[i]);
    k_wg<<<dim3(256, Lnt[i], 2), 256, 0, stream>>>(
        part, ysumb, Wgp, Wga, bgp, bga, xout, xout + STRX, i, Ltb[i], Lts[i], Lnt[i], Lsp[i]);
    float* tmp = xin; xin = xout; xout = tmp;
  }
  // final stream features at t=15 live in xin
  const float* fpp = xin + (size_t)15*N_E*32;
  const float* fpa = xin + STRX + (size_t)15*N_E*32;

  k_mlp<<<128,64,0,stream>>>(info, tra_feat, fpp, fpa, srv_emb, svc_emb,
                             qW0, qb0, qW1, qb1, qW2, qb2, qW3, qb3, qW4, qb4, qW5, qb5, out);
}